// Round 1
// baseline (90.467 us; speedup 1.0000x reference)
//
#include <hip/hip_runtime.h>

// NT-Xent (SimCLR) loss, B=2048, D=256, N=4096, T=0.5, eps=1e-8.
// R7: fuse k_rowlse into k_simlse. partial[32][4096] (1 MB round-trip) is
// replaced by device-scope atomicAdd into rowsum[4096] (16 KB, resolved at
// the coherence point -> no cross-XCD dirty-line hazard). A completion
// counter elects the LAST block (all 528 done) to finalize: 256 threads
// read rowsum+posv (32 KB, agent-scope loads), log, reduce, store out[0].
// This avoids R5's 30us single-block finalize (which read 512 KB of
// remote-dirty partial); here the finalizer reads 16x less, all coherent.
// 2 launches instead of 3: saves k_rowlse kernel (~2us) + gap (~2us),
// costs ~2us finalize tail. Fixed harness floor: ~42us d_ws poison fill
// + reset dispatches per iter.

#define NROWS 4096
#define DDIM 256
#define BHALF 2048
#define TILE 128
#define BK 64
#define LDP 72      // padded LDS row stride (shorts): 144B = 9*16B, 2-way banks (free)
#define NCB 32      // 4096/128 tile indices
#define NBLK 528    // NCB*(NCB+1)/2 upper-triangle blocks
#define INV_T 2.0f

typedef short bf16x8 __attribute__((ext_vector_type(8)));
typedef float f32x4 __attribute__((ext_vector_type(4)));

__device__ inline unsigned short f2bf(float f) {
    union { float f; unsigned u; } c; c.f = f;
    unsigned u = c.u + 0x7fffu + ((c.u >> 16) & 1u);  // RNE
    return (unsigned short)(u >> 16);
}

// ---- Kernel 1: row-normalize z=[z_i;z_j] into bf16 zn[4096][256] ----------
// Also zero-inits rowsum[4096], the completion counter, and out[0]
// (workspace is poisoned every iteration). Stream order guarantees
// visibility to k_simlse (kernel-boundary L2 writeback).
__global__ __launch_bounds__(256) void k_normalize(
    const float* __restrict__ zi, const float* __restrict__ zj,
    unsigned short* __restrict__ zn, float* __restrict__ rowsum,
    unsigned* __restrict__ counter, float* __restrict__ out) {
    if (blockIdx.x == 0 && threadIdx.x == 0) { *counter = 0u; out[0] = 0.f; }
    if (threadIdx.x < 4) rowsum[blockIdx.x * 4 + threadIdx.x] = 0.f;
    const int wave = threadIdx.x >> 6, lane = threadIdx.x & 63;
    const int row = blockIdx.x * 4 + wave;
    const float* src = (row < BHALF) ? (zi + row * DDIM)
                                     : (zj + (row - BHALF) * DDIM);
    const float4 v = ((const float4*)src)[lane];
    float ss = v.x * v.x + v.y * v.y + v.z * v.z + v.w * v.w;
    #pragma unroll
    for (int m = 1; m < 64; m <<= 1) ss += __shfl_xor(ss, m);
    const float scale = 1.0f / fmaxf(sqrtf(ss), 1e-8f);
    ushort4 o;
    o.x = f2bf(v.x * scale); o.y = f2bf(v.y * scale);
    o.z = f2bf(v.z * scale); o.w = f2bf(v.w * scale);
    ((ushort4*)(zn + row * DDIM))[lane] = o;
}

// ---- Kernel 2: upper-triangle sim GEMM + exp-sum + fused finalize ---------
// grid = 528 linear blocks -> (bx,by), by>=bx. Block 256 thr = 2x2 waves,
// each wave 64x64 via 4x4 mfma_f32_16x16x32_bf16. Row/col exp-sums go to
// rowsum[] via atomicAdd; last block to finish computes the loss.
__global__ __launch_bounds__(256) void k_simlse(
    const unsigned short* __restrict__ zn,
    float* __restrict__ rowsum,      // [4096] atomic accumulators
    float* __restrict__ posv,        // [4096]
    unsigned* __restrict__ counter,
    float* __restrict__ out) {
    __shared__ unsigned short As[TILE * LDP];
    __shared__ unsigned short Bs[TILE * LDP];
    __shared__ float pscratch[TILE];   // row sums cross-wc (reused by finalize)
    __shared__ float cscratch[TILE];   // col sums cross-wr
    __shared__ unsigned lastFlag;

    // triangle decode: block t -> (bx, by), by >= bx
    int t = blockIdx.x, bx = 0, rem = NCB;
    while (t >= rem) { t -= rem; ++bx; --rem; }
    const int by = bx + t;

    const int tid = threadIdx.x;
    const int wave = tid >> 6, lane = tid & 63;
    const int quad = lane >> 4, l15 = lane & 15;
    const int wr = wave >> 1, wc = wave & 1;
    const int rowBase = bx * TILE;
    const int colBase = by * TILE;

    f32x4 acc[4][4] = {};

    #pragma unroll
    for (int kb = 0; kb < DDIM / BK; ++kb) {
        __syncthreads();
        #pragma unroll
        for (int i = 0; i < 4; ++i) {
            const int flat = tid + i * 256;
            const int r = flat >> 3, c = flat & 7;
            *(bf16x8*)&As[r * LDP + c * 8] =
                *(const bf16x8*)&zn[(rowBase + r) * DDIM + kb * BK + c * 8];
            *(bf16x8*)&Bs[r * LDP + c * 8] =
                *(const bf16x8*)&zn[(colBase + r) * DDIM + kb * BK + c * 8];
        }
        __syncthreads();
        #pragma unroll
        for (int s = 0; s < 2; ++s) {
            bf16x8 af[4], bf[4];
            #pragma unroll
            for (int mt = 0; mt < 4; ++mt)
                af[mt] = *(const bf16x8*)&As[(wr * 64 + mt * 16 + l15) * LDP + s * 32 + quad * 8];
            #pragma unroll
            for (int nt = 0; nt < 4; ++nt)
                bf[nt] = *(const bf16x8*)&Bs[(wc * 64 + nt * 16 + l15) * LDP + s * 32 + quad * 8];
            #pragma unroll
            for (int mt = 0; mt < 4; ++mt)
                #pragma unroll
                for (int nt = 0; nt < 4; ++nt)
                    acc[mt][nt] = __builtin_amdgcn_mfma_f32_16x16x32_bf16(
                        af[mt], bf[nt], acc[mt][nt], 0, 0, 0);
        }
    }

    // Epilogue. C/D layout: col = lane&15, row = quad*4 + r.
    float rsum[4][4];          // [mt][r] row-sums (post-butterfly: all lanes)
    float csum[4] = {};        // [nt] per-lane col partial over 16 rows
    #pragma unroll
    for (int mt = 0; mt < 4; ++mt) {
        #pragma unroll
        for (int r = 0; r < 4; ++r) {
            const int grow = rowBase + wr * 64 + mt * 16 + quad * 4 + r;
            float s = 0.f;
            #pragma unroll
            for (int nt = 0; nt < 4; ++nt) {
                const int gcol = colBase + wc * 64 + nt * 16 + l15;
                const float simv = acc[mt][nt][r] * INV_T;
                const float e = (gcol != grow) ? __expf(simv) : 0.f;
                s += e;
                csum[nt] += e;
                if (gcol == grow + BHALF) {       // only in by==bx+16 blocks
                    // agent-scope stores: finalizer (other XCD) must see them
                    __hip_atomic_store(&posv[grow], simv, __ATOMIC_RELAXED,
                                       __HIP_MEMORY_SCOPE_AGENT);
                    __hip_atomic_store(&posv[gcol], simv, __ATOMIC_RELAXED,
                                       __HIP_MEMORY_SCOPE_AGENT);
                }
            }
            s += __shfl_xor(s, 1); s += __shfl_xor(s, 2);
            s += __shfl_xor(s, 4); s += __shfl_xor(s, 8);
            rsum[mt][r] = s;
        }
    }
    // col reduce across quads (row-index bits 4,5 of lane)
    #pragma unroll
    for (int nt = 0; nt < 4; ++nt) {
        csum[nt] += __shfl_xor(csum[nt], 16);
        csum[nt] += __shfl_xor(csum[nt], 32);
    }

    __syncthreads();
    if (wc == 0 && l15 == 0) {
        #pragma unroll
        for (int mt = 0; mt < 4; ++mt)
            #pragma unroll
            for (int r = 0; r < 4; ++r)
                pscratch[wr * 64 + mt * 16 + quad * 4 + r] = rsum[mt][r];
    }
    if (wr == 0 && quad == 0) {
        #pragma unroll
        for (int nt = 0; nt < 4; ++nt)
            cscratch[wc * 64 + nt * 16 + l15] = csum[nt];
    }
    __syncthreads();
    if (wc == 1 && l15 == 0) {    // row-sums -> rowsum[rowBase..] (atomic)
        #pragma unroll
        for (int mt = 0; mt < 4; ++mt)
            #pragma unroll
            for (int r = 0; r < 4; ++r) {
                const int lr = wr * 64 + mt * 16 + quad * 4 + r;
                atomicAdd(&rowsum[rowBase + lr], rsum[mt][r] + pscratch[lr]);
            }
    }
    if (bx != by && wr == 1 && quad == 0) {  // col-sums -> rowsum[colBase..]
        #pragma unroll
        for (int nt = 0; nt < 4; ++nt) {
            const int lc = wc * 64 + nt * 16 + l15;
            atomicAdd(&rowsum[colBase + lc], csum[nt] + cscratch[lc]);
        }
    }

    // ---- completion counter + last-block finalize -------------------------
    // __syncthreads drains this block's atomics (compiler emits
    // s_waitcnt vmcnt(0) before s_barrier); thread 0 then publishes with a
    // release-ordered counter increment.
    __syncthreads();
    if (tid == 0) {
        __threadfence();
        unsigned old = __hip_atomic_fetch_add(counter, 1u, __ATOMIC_ACQ_REL,
                                              __HIP_MEMORY_SCOPE_AGENT);
        lastFlag = (old == NBLK - 1) ? 1u : 0u;
    }
    __syncthreads();
    if (lastFlag) {
        __threadfence();
        float accv = 0.f;
        #pragma unroll
        for (int i = 0; i < NROWS / 256; ++i) {
            const int row = tid + i * 256;   // wave-coalesced agent loads
            const float s = __hip_atomic_load(&rowsum[row], __ATOMIC_RELAXED,
                                              __HIP_MEMORY_SCOPE_AGENT);
            const float pv = __hip_atomic_load(&posv[row], __ATOMIC_RELAXED,
                                               __HIP_MEMORY_SCOPE_AGENT);
            accv += __logf(s) - pv;
        }
        #pragma unroll
        for (int m = 1; m < 64; m <<= 1) accv += __shfl_xor(accv, m);
        if ((tid & 63) == 0) pscratch[tid >> 6] = accv;
        __syncthreads();
        if (tid == 0)
            out[0] = (pscratch[0] + pscratch[1] + pscratch[2] + pscratch[3])
                     * (1.0f / (float)NROWS);
    }
}

extern "C" void kernel_launch(void* const* d_in, const int* in_sizes, int n_in,
                              void* d_out, int out_size, void* d_ws, size_t ws_size,
                              hipStream_t stream) {
    const float* zi = (const float*)d_in[0];
    const float* zj = (const float*)d_in[1];
    float* out = (float*)d_out;

    unsigned short* zn = (unsigned short*)d_ws;                    // 2 MB
    float* posv = (float*)((char*)d_ws + NROWS * DDIM * 2);        // 16 KB
    float* rowsum = posv + NROWS;                                  // 16 KB
    unsigned* counter = (unsigned*)(rowsum + NROWS);               // 4 B

    k_normalize<<<NROWS / 4, 256, 0, stream>>>(zi, zj, zn, rowsum, counter, out);
    k_simlse<<<NBLK, 256, 0, stream>>>(zn, rowsum, posv, counter, out);
}

// Round 2
// 79.317 us; speedup vs baseline: 1.1406x; 1.1406x over previous
//
#include <hip/hip_runtime.h>

// NT-Xent (SimCLR) loss, B=2048, D=256, N=4096, T=0.5, eps=1e-8.
// R8: R7's fused finalize regressed +12us (528 per-block __threadfence +
// ACQ_REL counter RMWs = serialized L2 maintenance, plus grid-drain tail).
// Keep R6's 3-launch structure (stream-order visibility is free), but keep
// R7's good half: partial[32][4096] (512KB write + 528KB read, cross-XCD
// dirty) -> atomicAdd into rowsum[4096] (16KB, ~33 adders/address, no
// fences). k_rowlse now reads 32KB coherent instead of 528KB dirty.
// Fixed harness floor: ~42us d_ws poison fill + d_in restore per iter.

#define NROWS 4096
#define DDIM 256
#define BHALF 2048
#define TILE 128
#define BK 64
#define LDP 72      // padded LDS row stride (shorts): 144B = 9*16B, 2-way banks (free)
#define NCB 32      // 4096/128 tile indices
#define NBLK 528    // NCB*(NCB+1)/2 upper-triangle blocks
#define INV_T 2.0f

typedef short bf16x8 __attribute__((ext_vector_type(8)));
typedef float f32x4 __attribute__((ext_vector_type(4)));

__device__ inline unsigned short f2bf(float f) {
    union { float f; unsigned u; } c; c.f = f;
    unsigned u = c.u + 0x7fffu + ((c.u >> 16) & 1u);  // RNE
    return (unsigned short)(u >> 16);
}

// ---- Kernel 1: row-normalize z=[z_i;z_j] into bf16 zn[4096][256] ----------
// Also zero-inits rowsum[4096] and out[0] (workspace is poisoned every
// iteration). Stream order guarantees visibility to k_simlse.
__global__ __launch_bounds__(256) void k_normalize(
    const float* __restrict__ zi, const float* __restrict__ zj,
    unsigned short* __restrict__ zn, float* __restrict__ rowsum,
    float* __restrict__ out) {
    if (blockIdx.x == 0 && threadIdx.x == 0) out[0] = 0.f;
    if (threadIdx.x < 4) rowsum[blockIdx.x * 4 + threadIdx.x] = 0.f;
    const int wave = threadIdx.x >> 6, lane = threadIdx.x & 63;
    const int row = blockIdx.x * 4 + wave;
    const float* src = (row < BHALF) ? (zi + row * DDIM)
                                     : (zj + (row - BHALF) * DDIM);
    const float4 v = ((const float4*)src)[lane];
    float ss = v.x * v.x + v.y * v.y + v.z * v.z + v.w * v.w;
    #pragma unroll
    for (int m = 1; m < 64; m <<= 1) ss += __shfl_xor(ss, m);
    const float scale = 1.0f / fmaxf(sqrtf(ss), 1e-8f);
    ushort4 o;
    o.x = f2bf(v.x * scale); o.y = f2bf(v.y * scale);
    o.z = f2bf(v.z * scale); o.w = f2bf(v.w * scale);
    ((ushort4*)(zn + row * DDIM))[lane] = o;
}

// ---- Kernel 2: upper-triangle LDS-tiled sim GEMM + exp-sum ----------------
// grid = 528 linear blocks -> (bx,by), by>=bx. Block 256 thr = 2x2 waves,
// each wave 64x64 via 4x4 mfma_f32_16x16x32_bf16. Row/col exp-sums
// accumulate into rowsum[] via device-scope atomicAdd (no fences needed;
// kernel boundary is the release point for k_rowlse).
__global__ __launch_bounds__(256) void k_simlse(
    const unsigned short* __restrict__ zn,
    float* __restrict__ rowsum,      // [4096] atomic accumulators
    float* __restrict__ posv) {      // [4096]
    __shared__ unsigned short As[TILE * LDP];
    __shared__ unsigned short Bs[TILE * LDP];
    __shared__ float pscratch[TILE];   // row sums cross-wc
    __shared__ float cscratch[TILE];   // col sums cross-wr

    // triangle decode: block t -> (bx, by), by >= bx
    int t = blockIdx.x, bx = 0, rem = NCB;
    while (t >= rem) { t -= rem; ++bx; --rem; }
    const int by = bx + t;

    const int tid = threadIdx.x;
    const int wave = tid >> 6, lane = tid & 63;
    const int quad = lane >> 4, l15 = lane & 15;
    const int wr = wave >> 1, wc = wave & 1;
    const int rowBase = bx * TILE;
    const int colBase = by * TILE;

    f32x4 acc[4][4] = {};

    #pragma unroll
    for (int kb = 0; kb < DDIM / BK; ++kb) {
        __syncthreads();
        #pragma unroll
        for (int i = 0; i < 4; ++i) {
            const int flat = tid + i * 256;
            const int r = flat >> 3, c = flat & 7;
            *(bf16x8*)&As[r * LDP + c * 8] =
                *(const bf16x8*)&zn[(rowBase + r) * DDIM + kb * BK + c * 8];
            *(bf16x8*)&Bs[r * LDP + c * 8] =
                *(const bf16x8*)&zn[(colBase + r) * DDIM + kb * BK + c * 8];
        }
        __syncthreads();
        #pragma unroll
        for (int s = 0; s < 2; ++s) {
            bf16x8 af[4], bf[4];
            #pragma unroll
            for (int mt = 0; mt < 4; ++mt)
                af[mt] = *(const bf16x8*)&As[(wr * 64 + mt * 16 + l15) * LDP + s * 32 + quad * 8];
            #pragma unroll
            for (int nt = 0; nt < 4; ++nt)
                bf[nt] = *(const bf16x8*)&Bs[(wc * 64 + nt * 16 + l15) * LDP + s * 32 + quad * 8];
            #pragma unroll
            for (int mt = 0; mt < 4; ++mt)
                #pragma unroll
                for (int nt = 0; nt < 4; ++nt)
                    acc[mt][nt] = __builtin_amdgcn_mfma_f32_16x16x32_bf16(
                        af[mt], bf[nt], acc[mt][nt], 0, 0, 0);
        }
    }

    // Epilogue. C/D layout: col = lane&15, row = quad*4 + r.
    float rsum[4][4];          // [mt][r] row-sums (post-butterfly: all lanes)
    float csum[4] = {};        // [nt] per-lane col partial over 16 rows
    #pragma unroll
    for (int mt = 0; mt < 4; ++mt) {
        #pragma unroll
        for (int r = 0; r < 4; ++r) {
            const int grow = rowBase + wr * 64 + mt * 16 + quad * 4 + r;
            float s = 0.f;
            #pragma unroll
            for (int nt = 0; nt < 4; ++nt) {
                const int gcol = colBase + wc * 64 + nt * 16 + l15;
                const float simv = acc[mt][nt][r] * INV_T;
                const float e = (gcol != grow) ? __expf(simv) : 0.f;
                s += e;
                csum[nt] += e;
                if (gcol == grow + BHALF) {       // only in by==bx+16 blocks
                    posv[grow] = simv;            // sim symmetric -> both rows
                    posv[gcol] = simv;
                }
            }
            s += __shfl_xor(s, 1); s += __shfl_xor(s, 2);
            s += __shfl_xor(s, 4); s += __shfl_xor(s, 8);
            rsum[mt][r] = s;
        }
    }
    // col reduce across quads (row-index bits 4,5 of lane)
    #pragma unroll
    for (int nt = 0; nt < 4; ++nt) {
        csum[nt] += __shfl_xor(csum[nt], 16);
        csum[nt] += __shfl_xor(csum[nt], 32);
    }

    __syncthreads();
    if (wc == 0 && l15 == 0) {
        #pragma unroll
        for (int mt = 0; mt < 4; ++mt)
            #pragma unroll
            for (int r = 0; r < 4; ++r)
                pscratch[wr * 64 + mt * 16 + quad * 4 + r] = rsum[mt][r];
    }
    if (wr == 0 && quad == 0) {
        #pragma unroll
        for (int nt = 0; nt < 4; ++nt)
            cscratch[wc * 64 + nt * 16 + l15] = csum[nt];
    }
    __syncthreads();
    if (wc == 1 && l15 == 0) {    // row-sums -> rowsum[rowBase..] (atomic)
        #pragma unroll
        for (int mt = 0; mt < 4; ++mt)
            #pragma unroll
            for (int r = 0; r < 4; ++r) {
                const int lr = wr * 64 + mt * 16 + quad * 4 + r;
                atomicAdd(&rowsum[rowBase + lr], rsum[mt][r] + pscratch[lr]);
            }
    }
    if (bx != by && wr == 1 && quad == 0) {  // col-sums -> rowsum[colBase..]
        #pragma unroll
        for (int nt = 0; nt < 4; ++nt) {
            const int lc = wc * 64 + nt * 16 + l15;
            atomicAdd(&rowsum[colBase + lc], csum[nt] + cscratch[lc]);
        }
    }
}

// ---- Kernel 3: 16-block rowlse (32 KB read) + atomic final sum ------------
__global__ __launch_bounds__(256) void k_rowlse(
    const float* __restrict__ rowsum, const float* __restrict__ posv,
    float* __restrict__ out) {
    __shared__ float red[4];
    const int tid = threadIdx.x;
    const int row = blockIdx.x * 256 + tid;
    float v = __logf(rowsum[row]) - posv[row];
    #pragma unroll
    for (int m = 1; m < 64; m <<= 1) v += __shfl_xor(v, m);
    if ((tid & 63) == 0) red[tid >> 6] = v;
    __syncthreads();
    if (tid == 0)
        atomicAdd(out, (red[0] + red[1] + red[2] + red[3]) * (1.0f / (float)NROWS));
}

extern "C" void kernel_launch(void* const* d_in, const int* in_sizes, int n_in,
                              void* d_out, int out_size, void* d_ws, size_t ws_size,
                              hipStream_t stream) {
    const float* zi = (const float*)d_in[0];
    const float* zj = (const float*)d_in[1];
    float* out = (float*)d_out;

    unsigned short* zn = (unsigned short*)d_ws;                    // 2 MB
    float* posv = (float*)((char*)d_ws + NROWS * DDIM * 2);        // 16 KB
    float* rowsum = posv + NROWS;                                  // 16 KB

    k_normalize<<<NROWS / 4, 256, 0, stream>>>(zi, zj, zn, rowsum, out);
    k_simlse<<<NBLK, 256, 0, stream>>>(zn, rowsum, posv);
    k_rowlse<<<16, 256, 0, stream>>>(rowsum, posv, out);
}